// Round 7
// baseline (213.323 us; speedup 1.0000x reference)
//
#include <hip/hip_runtime.h>
#include <math.h>

typedef short bf16x8 __attribute__((ext_vector_type(8)));
typedef float f32x4 __attribute__((ext_vector_type(4)));

#define BB 64
#define NN 512
#define NH 4
#define FI 16
#define FO 64
#define HD1 1024
#define HD2 512
#define ODIM 40

__device__ __forceinline__ unsigned short f2bf(float f) {
    unsigned u = __float_as_uint(f);
    u += 0x7fffu + ((u >> 16) & 1u);        // RNE
    return (unsigned short)(u >> 16);
}
__device__ __forceinline__ unsigned pack2(float a, float b) {
    return (unsigned)f2bf(a) | ((unsigned)f2bf(b) << 16);
}
// async global->LDS, 16B per lane; lds dest = wave-uniform base + lane*16
__device__ __forceinline__ void gload16(const void* g, void* l) {
    __builtin_amdgcn_global_load_lds(
        (const __attribute__((address_space(1))) unsigned int*)g,
        (__attribute__((address_space(3))) unsigned int*)l,
        16, 0, 0);
}

// ---------------- kernel 0: wa[h][i] = sum_o w[h][i][o] * a_{src,dst}[h][o] ----------------
__global__ void k_wa(const float* __restrict__ w, const float* __restrict__ a_src,
                     const float* __restrict__ a_dst, float* __restrict__ wa)
{
    int t = threadIdx.x;      // 0..63 = h*16+i
    int h = t >> 4;
    float s = 0.f, d = 0.f;
    for (int o = 0; o < FO; ++o) {
        float wv = w[t*FO + o];
        s = fmaf(wv, a_src[h*FO + o], s);
        d = fmaf(wv, a_dst[h*FO + o], d);
    }
    wa[t] = s; wa[64 + t] = d;
}

// ---------------- kernel 1: projection -> hpT bf16 (transposed), asrc/adst, gat=bias+skip ----------------
__global__ __launch_bounds__(256) void k_proj2(
    const float* __restrict__ x, const float* __restrict__ w,
    const float* __restrict__ bias, const float* __restrict__ wa,
    short* __restrict__ hpT,           // [B*H][64 o][512 n] bf16
    float* __restrict__ asrc, float* __restrict__ adst,
    float* __restrict__ gat)
{
    __shared__ float xS[64][20];
    __shared__ float gS[NH][64][64];
    int b = blockIdx.y;
    int n0 = blockIdx.x * 64;
    int t = threadIdx.x;
    int h = t >> 6, o = t & 63;
    {
        int n = t >> 2, q = t & 3;
        float4 v = *(const float4*)&x[((size_t)b*NN + n0 + n)*FI + q*4];
        *(float4*)&xS[n][q*4] = v;
    }
    float wreg[16];
#pragma unroll
    for (int i = 0; i < FI; ++i) wreg[i] = w[(h*FI + i)*FO + o];
    __syncthreads();

    size_t hbase = ((size_t)(b*NH + h)*FO + o) * NN + n0;
    for (int nc = 0; nc < 8; ++nc) {
        float acc[8];
#pragma unroll
        for (int k = 0; k < 8; ++k) {
            int n = nc*8 + k;
            float4 a0 = *(const float4*)&xS[n][0];
            float4 a1 = *(const float4*)&xS[n][4];
            float4 a2 = *(const float4*)&xS[n][8];
            float4 a3 = *(const float4*)&xS[n][12];
            float sA = fmaf(a0.x, wreg[0], fmaf(a0.y, wreg[1], fmaf(a0.z, wreg[2], a0.w*wreg[3])));
            float sB = fmaf(a1.x, wreg[4], fmaf(a1.y, wreg[5], fmaf(a1.z, wreg[6], a1.w*wreg[7])));
            float sC = fmaf(a2.x, wreg[8], fmaf(a2.y, wreg[9], fmaf(a2.z, wreg[10], a2.w*wreg[11])));
            float sD = fmaf(a3.x, wreg[12], fmaf(a3.y, wreg[13], fmaf(a3.z, wreg[14], a3.w*wreg[15])));
            float s = (sA + sB) + (sC + sD);
            acc[k] = s;
            gS[h][n][o] = s;
        }
        uint4 p;
        p.x = pack2(acc[0], acc[1]); p.y = pack2(acc[2], acc[3]);
        p.z = pack2(acc[4], acc[5]); p.w = pack2(acc[6], acc[7]);
        *(uint4*)&hpT[hbase + nc*8] = p;
    }
    {
        int n = o;
        float vs = 0.f, vd = 0.f;
#pragma unroll
        for (int i = 0; i < FI; ++i) {
            float xv = xS[n][i];
            vs = fmaf(xv, wa[h*FI + i], vs);
            vd = fmaf(xv, wa[64 + h*FI + i], vd);
        }
        asrc[(size_t)(b*NH + h)*NN + n0 + n] = vs;
        adst[(size_t)(b*NH + h)*NN + n0 + n] = vd;
    }
    __syncthreads();
#pragma unroll
    for (int r = 0; r < 16; ++r) {
        int idx = t + r*256;
        int n = idx >> 6, oo = idx & 63;
        float g = bias[oo] + ((gS[0][n][oo] + gS[1][n][oo]) + (gS[2][n][oo] + gS[3][n][oo]));
        gat[((size_t)b*NN + n0 + n)*FO + oo] = g;
    }
}

// ---------------- kernel 2: per-row softmax stats (max, 1/sumexp), 1 row/thread ----------------
__global__ __launch_bounds__(256) void k_stats(
    const float* __restrict__ asrc, const float* __restrict__ adst,
    float* __restrict__ rm, float* __restrict__ rr)
{
    int bh = blockIdx.x;              // b*NH + h
    __shared__ float d[NN];
    int t = threadIdx.x;
    for (int j = t; j < NN; j += 256) d[j] = adst[bh * NN + j];
    __syncthreads();
    int i = blockIdx.y * 256 + t;
    float s = asrc[bh * NN + i];
    float m = -INFINITY;
    for (int j = 0; j < NN; ++j) {
        float v = s * d[j];
        v = fmaxf(v, 0.2f * v);
        m = fmaxf(m, v);
    }
    float sum = 0.f;
    for (int j = 0; j < NN; ++j) {
        float v = s * d[j];
        v = fmaxf(v, 0.2f * v);
        sum += __expf(v - m);
    }
    rm[bh * NN + i] = m;
    rr[bh * NN + i] = 1.0f / sum;     // mask applied AFTER softmax
}

// ---------------- kernel 3: MFMA attention, V tile staged via global_load_lds ----------------
__global__ __launch_bounds__(256) void k_attn2(
    const short* __restrict__ hpT, const float* __restrict__ mask,
    const float* __restrict__ asrc, const float* __restrict__ rm, const float* __restrict__ rr,
    const float* __restrict__ adst,
    float* __restrict__ gat)
{
    __shared__ float dS[NH*NN];       // 8KB
    __shared__ char vts[16384];       // V tile [256 (h,o) rows][32 j] bf16, slot-swizzled
    int b = blockIdx.y;
    int i0blk = blockIdx.x * 64;
    int t = threadIdx.x;
#pragma unroll
    for (int r = 0; r < 8; ++r) {
        int idx = t + r*256;
        dS[idx] = adst[(size_t)b*(NH*NN) + idx];
    }
    int wv = t >> 6, lane = t & 63;
    int li = lane & 15, kq = lane >> 4;
    int i = i0blk + wv*16 + li;
    float s[NH], m[NH], rcp[NH];
#pragma unroll
    for (int h = 0; h < NH; ++h) {
        size_t ix = (size_t)(b*NH + h)*NN + i;
        s[h] = asrc[ix]; m[h] = rm[ix]; rcp[h] = rr[ix];
    }
    __syncthreads();
    f32x4 acc[4];
#pragma unroll
    for (int ot = 0; ot < 4; ++ot) acc[ot] = (f32x4)0.f;

    const float* mrow = &mask[((size_t)b*NN + i)*NN];
    for (int jt = 0; jt < 16; ++jt) {
        int j0 = jt*32;
#pragma unroll
        for (int q = 0; q < 4; ++q) {
            int flatB = wv*4096 + q*1024 + lane*16;
            int row = flatB >> 6;
            int slotS = ((flatB >> 4) & 3) ^ ((row >> 1) & 3);
            const short* src = hpT + ((size_t)b*256 + row)*NN + j0 + slotS*8;
            gload16(src, vts + wv*4096 + q*1024);
        }
        __syncthreads();   // drains vmcnt -> tile visible
        float4 mk0 = *(const float4*)&mrow[j0 + kq*8];
        float4 mk1 = *(const float4*)&mrow[j0 + kq*8 + 4];
        float mk[8] = {mk0.x, mk0.y, mk0.z, mk0.w, mk1.x, mk1.y, mk1.z, mk1.w};
#pragma unroll
        for (int h = 0; h < NH; ++h) {
            float4 d0 = *(const float4*)&dS[h*NN + j0 + kq*8];
            float4 d1 = *(const float4*)&dS[h*NN + j0 + kq*8 + 4];
            float dv[8] = {d0.x,d0.y,d0.z,d0.w,d1.x,d1.y,d1.z,d1.w};
            union { bf16x8 v; unsigned u[4]; } pf;
#pragma unroll
            for (int q = 0; q < 4; ++q) {
                float v0 = s[h]*dv[2*q];   v0 = fmaxf(v0, 0.2f*v0);
                float v1 = s[h]*dv[2*q+1]; v1 = fmaxf(v1, 0.2f*v1);
                float e0 = __expf(v0 - m[h]) * rcp[h] * mk[2*q];
                float e1 = __expf(v1 - m[h]) * rcp[h] * mk[2*q+1];
                pf.u[q] = pack2(e0, e1);
            }
#pragma unroll
            for (int ot = 0; ot < 4; ++ot) {
                int row = h*64 + ot*16 + li;
                int slot = kq ^ ((row >> 1) & 3);
                bf16x8 vf = *(bf16x8*)(vts + row*64 + slot*16);
                acc[ot] = __builtin_amdgcn_mfma_f32_16x16x32_bf16(pf.v, vf, acc[ot], 0, 0, 0);
            }
        }
        __syncthreads();   // all reads done before next stage overwrites
    }
#pragma unroll
    for (int ot = 0; ot < 4; ++ot) {
#pragma unroll
        for (int g = 0; g < 4; ++g) {
            int ii = i0blk + wv*16 + kq*4 + g;
            int oo = ot*16 + li;
            size_t ix = ((size_t)b*NN + ii)*FO + oo;
            gat[ix] += acc[ot][g];
        }
    }
}

// ---------------- kernel 4a: convert MLP weights to bf16, transposed (n-major) ----------------
__global__ __launch_bounds__(256) void k_conv(
    const float* __restrict__ W1, const float* __restrict__ W2, const float* __restrict__ W3,
    short* __restrict__ w1t, short* __restrict__ w2t, short* __restrict__ w3t)
{
    int idx = blockIdx.x * 256 + threadIdx.x;
    if (idx < HD1*FO) {
        int n = idx >> 6, k = idx & 63;
        w1t[idx] = (short)f2bf(W1[k*HD1 + n]);
    } else if (idx < HD1*FO + HD2*HD1) {
        int i2 = idx - HD1*FO;
        int n = i2 >> 10, k = i2 & 1023;
        w2t[i2] = (short)f2bf(W2[k*HD2 + n]);
    } else if (idx < HD1*FO + HD2*HD1 + 48*HD2) {
        int i3 = idx - (HD1*FO + HD2*HD1);
        int n = i3 >> 9, k = i3 & 511;
        w3t[i3] = (short)(n < ODIM ? f2bf(W3[k*ODIM + n]) : 0);
    }
}

// ---------------- kernel 4b: GEMM1 [32768x64]@[64x1024] -> relu -> h1g bf16 (global) ----------------
__global__ __launch_bounds__(256, 2) void k_mlpA(
    const float* __restrict__ gat,
    const short* __restrict__ w1t, const float* __restrict__ b1,
    short* __restrict__ h1g)
{
    __shared__ char a0b[8192];        // [64 m][64 k] bf16, XOR-swizzled
    int t = threadIdx.x;
    int lane = t & 63, wave = t >> 6;
    int li = lane & 15, kq = lane >> 4;
    int m0 = blockIdx.x * 64;

    {   // relu(gat) -> bf16 -> a0 (each thread: 1 row-quarter = 16 floats)
        int row = t >> 2, c0 = (t & 3) * 16;
        const float4* g = (const float4*)&gat[(size_t)(m0 + row) * FO + c0];
        float4 v0 = g[0], v1 = g[1], v2 = g[2], v3 = g[3];
        uint4 p0, p1;
        p0.x = pack2(fmaxf(v0.x,0.f), fmaxf(v0.y,0.f));
        p0.y = pack2(fmaxf(v0.z,0.f), fmaxf(v0.w,0.f));
        p0.z = pack2(fmaxf(v1.x,0.f), fmaxf(v1.y,0.f));
        p0.w = pack2(fmaxf(v1.z,0.f), fmaxf(v1.w,0.f));
        p1.x = pack2(fmaxf(v2.x,0.f), fmaxf(v2.y,0.f));
        p1.y = pack2(fmaxf(v2.z,0.f), fmaxf(v2.w,0.f));
        p1.z = pack2(fmaxf(v3.x,0.f), fmaxf(v3.y,0.f));
        p1.w = pack2(fmaxf(v3.z,0.f), fmaxf(v3.w,0.f));
        int base = row*128 + c0*2;
        *(uint4*)(a0b + (base ^ ((row&7)<<4)))      = p0;
        *(uint4*)(a0b + ((base+16) ^ ((row&7)<<4))) = p1;
    }
    __syncthreads();

    for (int c = 0; c < 4; ++c) {     // wave owns 256 n-cols
        int n0 = wave * 256 + c * 64;
        f32x4 acc[4][4];
#pragma unroll
        for (int mt = 0; mt < 4; ++mt)
#pragma unroll
            for (int nt = 0; nt < 4; ++nt) acc[mt][nt] = (f32x4)0.f;
#pragma unroll
        for (int ks = 0; ks < 2; ++ks) {
            int k0 = ks * 32;
            bf16x8 xf[4];
#pragma unroll
            for (int mt = 0; mt < 4; ++mt) {
                int row = mt * 16 + li;
                int addr = (row * 128 + k0 * 2 + kq * 16) ^ ((row & 7) << 4);
                xf[mt] = *(bf16x8*)(a0b + addr);
            }
#pragma unroll
            for (int nt = 0; nt < 4; ++nt) {
                int col = n0 + nt * 16 + li;
                bf16x8 wf = *(const bf16x8*)(w1t + col * 64 + k0 + kq * 8);
#pragma unroll
                for (int mt = 0; mt < 4; ++mt)
                    acc[mt][nt] = __builtin_amdgcn_mfma_f32_16x16x32_bf16(wf, xf[mt], acc[mt][nt], 0, 0, 0);
            }
        }
#pragma unroll
        for (int mt = 0; mt < 4; ++mt)
#pragma unroll
            for (int nt = 0; nt < 4; ++nt) {
                int m = mt * 16 + li;
                int nb = n0 + nt * 16 + kq * 4;
                float4 bb = *(const float4*)&b1[nb];
                float v0 = fmaxf(acc[mt][nt][0] + bb.x, 0.f);
                float v1 = fmaxf(acc[mt][nt][1] + bb.y, 0.f);
                float v2 = fmaxf(acc[mt][nt][2] + bb.z, 0.f);
                float v3 = fmaxf(acc[mt][nt][3] + bb.w, 0.f);
                uint2 pw; pw.x = pack2(v0, v1); pw.y = pack2(v2, v3);
                *(uint2*)&h1g[(size_t)(m0 + m) * HD1 + nb] = pw;
            }
    }
}

// ---------------- kernel 4c: GEMM2 (dbuf-pipelined LDS staging) + GEMM3 -> out ----------------
// LDS: 2 x {h1s [64m][32k] 4KB + w2s [512n][32k] 32KB} = 72KB -> 2 blocks/CU.
// h2 [64][512] bf16 (64KB, XOR-swizzled) aliases the dbuf after GEMM2.
#define BUFSZ 36864
__global__ __launch_bounds__(256, 2) void k_mlpB(
    const short* __restrict__ h1g,
    const short* __restrict__ w2t, const float* __restrict__ b2,
    const short* __restrict__ w3t, const float* __restrict__ b3,
    float* __restrict__ out)
{
    extern __shared__ char smem[];    // 73728 B
    int t = threadIdx.x;
    int lane = t & 63, wave = t >> 6;
    int li = lane & 15, kq = lane >> 4;
    int m0 = blockIdx.x * 64;

    // ---- stage slice ks into buf i: h1s (1 gload/wave) + w2s (8 gloads/wave)
    auto STAGE = [&](int i, int ks) {
        char* base = smem + i * BUFSZ;
        {
            int row = wave * 16 + (lane >> 2);
            int slotS = (lane & 3) ^ ((row >> 1) & 3);
            const short* src = h1g + (size_t)(m0 + row) * HD1 + ks * 32 + slotS * 8;
            gload16(src, base + wave * 1024);
        }
#pragma unroll
        for (int q = 0; q < 8; ++q) {
            int flatB = wave * 8192 + q * 1024 + lane * 16;
            int n = flatB >> 6;
            int slotS = ((flatB >> 4) & 3) ^ ((n >> 1) & 3);
            const short* src = w2t + (size_t)n * HD1 + ks * 32 + slotS * 8;
            gload16(src, base + 4096 + wave * 8192 + q * 1024);
        }
    };

    f32x4 acc2[4][8];
#pragma unroll
    for (int mt = 0; mt < 4; ++mt)
#pragma unroll
        for (int nt = 0; nt < 8; ++nt) acc2[mt][nt] = (f32x4)0.f;

    STAGE(0, 0);
    __syncthreads();                  // drains vmcnt -> buf0 ready
    for (int ks = 0; ks < 32; ++ks) {
        int cur = ks & 1;
        if (ks < 31) STAGE(cur ^ 1, ks + 1);   // issue-early: hides under compute
        char* base = smem + cur * BUFSZ;
        bf16x8 xf[4], wf[8];
#pragma unroll
        for (int mt = 0; mt < 4; ++mt) {
            int m = mt * 16 + li;
            int slot = kq ^ ((m >> 1) & 3);
            xf[mt] = *(bf16x8*)(base + m * 64 + slot * 16);
        }
#pragma unroll
        for (int nt = 0; nt < 8; ++nt) {
            int n = wave * 128 + nt * 16 + li;
            int slot = kq ^ ((n >> 1) & 3);
            wf[nt] = *(bf16x8*)(base + 4096 + n * 64 + slot * 16);
        }
#pragma unroll
        for (int nt = 0; nt < 8; ++nt)
#pragma unroll
            for (int mt = 0; mt < 4; ++mt)
                acc2[mt][nt] = __builtin_amdgcn_mfma_f32_16x16x32_bf16(wf[nt], xf[mt], acc2[mt][nt], 0, 0, 0);
        __syncthreads();              // vmcnt(0)+barrier: next buf landed, reads done
    }

    // ---- h2 = relu(acc2 + b2) -> bf16 -> LDS [64][512] swizzled (aliases dbuf)
#pragma unroll
    for (int mt = 0; mt < 4; ++mt)
#pragma unroll
        for (int nt = 0; nt < 8; ++nt) {
            int m = mt * 16 + li;
            int nb = wave * 128 + nt * 16 + kq * 4;
            float4 bb = *(const float4*)&b2[nb];
            float v0 = fmaxf(acc2[mt][nt][0] + bb.x, 0.f);
            float v1 = fmaxf(acc2[mt][nt][1] + bb.y, 0.f);
            float v2 = fmaxf(acc2[mt][nt][2] + bb.z, 0.f);
            float v3 = fmaxf(acc2[mt][nt][3] + bb.w, 0.f);
            uint2 pw; pw.x = pack2(v0, v1); pw.y = pack2(v2, v3);
            int addr = (m * 1024 + nb * 2) ^ ((m & 7) << 4);
            *(uint2*)(smem + addr) = pw;
        }
    __syncthreads();

    // ---- GEMM3 [64x512]@[512x48]: wave owns 16 m-rows, full K
    f32x4 acc3[3];
#pragma unroll
    for (int nt = 0; nt < 3; ++nt) acc3[nt] = (f32x4)0.f;
#pragma unroll
    for (int ks = 0; ks < 16; ++ks) {
        int k0 = ks * 32;
        int m = wave * 16 + li;
        int addr = (m * 1024 + k0 * 2 + kq * 16) ^ ((m & 7) << 4);
        bf16x8 xf = *(bf16x8*)(smem + addr);
#pragma unroll
        for (int nt = 0; nt < 3; ++nt) {
            int col = nt * 16 + li;
            bf16x8 wf = *(const bf16x8*)(w3t + col * 512 + k0 + kq * 8);
            acc3[nt] = __builtin_amdgcn_mfma_f32_16x16x32_bf16(wf, xf, acc3[nt], 0, 0, 0);
        }
    }
    // out: lane holds m = wave*16+li, n = nt*16 + kq*4 + g
#pragma unroll
    for (int nt = 0; nt < 3; ++nt)
#pragma unroll
        for (int g = 0; g < 4; ++g) {
            int n = nt * 16 + kq * 4 + g;
            if (n < ODIM) {
                int m = wave * 16 + li;
                float s = acc3[nt][g] + b3[n];
                s = 1.f / (1.f + __expf(-s));
                s = fminf(fmaxf(s, 0.01f), 0.99f);
                out[(size_t)(m0 + m) * ODIM + n] = s;
            }
        }
}

extern "C" void kernel_launch(void* const* d_in, const int* in_sizes, int n_in,
                              void* d_out, int out_size, void* d_ws, size_t ws_size,
                              hipStream_t stream)
{
    const float* x     = (const float*)d_in[0];
    const float* mask  = (const float*)d_in[1];
    const float* w     = (const float*)d_in[2];
    const float* a_src = (const float*)d_in[3];
    const float* a_dst = (const float*)d_in[4];
    const float* bias  = (const float*)d_in[5];
    const float* W1    = (const float*)d_in[6];
    const float* b1    = (const float*)d_in[7];
    const float* W2    = (const float*)d_in[8];
    const float* b2    = (const float*)d_in[9];
    const float* W3    = (const float*)d_in[10];
    const float* b3    = (const float*)d_in[11];
    float* out = (float*)d_out;

    char* p = (char*)d_ws;
    // h1g [32768][1024] bf16 (64MB) overlays hpT/asrc/adst/rm/rr (dead before k_mlpA)
    short* h1g = (short*)p;
    short* hpT = (short*)p;  p += (size_t)BB*NH*FO*NN*2;   // 16.78 MB
    float* asrc = (float*)p; p += (size_t)BB*NH*NN*4;
    float* adst = (float*)p; p += (size_t)BB*NH*NN*4;
    float* rm   = (float*)p; p += (size_t)BB*NH*NN*4;
    float* rr   = (float*)p; p += (size_t)BB*NH*NN*4;
    p = (char*)d_ws + (size_t)BB*NN*HD1*2;                 // past h1g (67.1 MB)
    float* gat  = (float*)p; p += (size_t)BB*NN*FO*4;      // 8.39 MB
    short* w1t  = (short*)p; p += (size_t)HD1*FO*2;
    short* w2t  = (short*)p; p += (size_t)HD2*HD1*2;
    short* w3t  = (short*)p; p += (size_t)48*HD2*2;
    float* wa   = (float*)p; p += 128*4;                   // total ~76.7 MB

    k_wa   <<<1, 64, 0, stream>>>(w, a_src, a_dst, wa);
    k_conv <<<(HD1*FO + HD2*HD1 + 48*HD2)/256, 256, 0, stream>>>(W1, W2, W3, w1t, w2t, w3t);
    k_proj2<<<dim3(NN/64, BB), 256, 0, stream>>>(x, w, bias, wa, hpT, asrc, adst, gat);
    k_stats<<<dim3(BB*NH, 2), 256, 0, stream>>>(asrc, adst, rm, rr);
    k_attn2<<<dim3(NN/64, BB), 256, 0, stream>>>(hpT, mask, asrc, rm, rr, adst, gat);
    k_mlpA <<<BB*NN/64, 256, 0, stream>>>(gat, w1t, b1, h1g);
    k_mlpB <<<BB*NN/64, 256, 73728, stream>>>(h1g, w2t, b2, w3t, b3, out);
}

// Round 8
// 208.466 us; speedup vs baseline: 1.0233x; 1.0233x over previous
//
#include <hip/hip_runtime.h>
#include <math.h>

typedef short bf16x8 __attribute__((ext_vector_type(8)));
typedef float f32x4 __attribute__((ext_vector_type(4)));

#define BB 64
#define NN 512
#define NH 4
#define FI 16
#define FO 64
#define HD1 1024
#define HD2 512
#define ODIM 40

__device__ __forceinline__ unsigned short f2bf(float f) {
    unsigned u = __float_as_uint(f);
    u += 0x7fffu + ((u >> 16) & 1u);        // RNE
    return (unsigned short)(u >> 16);
}
__device__ __forceinline__ unsigned pack2(float a, float b) {
    return (unsigned)f2bf(a) | ((unsigned)f2bf(b) << 16);
}
// async global->LDS, 16B per lane; lds dest = wave-uniform base + lane*16
__device__ __forceinline__ void gload16(const void* g, void* l) {
    __builtin_amdgcn_global_load_lds(
        (const __attribute__((address_space(1))) unsigned int*)g,
        (__attribute__((address_space(3))) unsigned int*)l,
        16, 0, 0);
}

// ---------------- kernel 0: wa[h][i] = sum_o w[h][i][o] * a_{src,dst}[h][o] ----------------
__global__ void k_wa(const float* __restrict__ w, const float* __restrict__ a_src,
                     const float* __restrict__ a_dst, float* __restrict__ wa)
{
    int t = threadIdx.x;      // 0..63 = h*16+i
    int h = t >> 4;
    float s = 0.f, d = 0.f;
    for (int o = 0; o < FO; ++o) {
        float wv = w[t*FO + o];
        s = fmaf(wv, a_src[h*FO + o], s);
        d = fmaf(wv, a_dst[h*FO + o], d);
    }
    wa[t] = s; wa[64 + t] = d;
}

// ---------------- kernel 1: projection -> hpT bf16 (transposed), asrc/adst, gat=bias+skip ----------------
__global__ __launch_bounds__(256) void k_proj2(
    const float* __restrict__ x, const float* __restrict__ w,
    const float* __restrict__ bias, const float* __restrict__ wa,
    short* __restrict__ hpT,           // [B*H][64 o][512 n] bf16
    float* __restrict__ asrc, float* __restrict__ adst,
    float* __restrict__ gat)
{
    __shared__ float xS[64][20];
    __shared__ float gS[NH][64][64];
    int b = blockIdx.y;
    int n0 = blockIdx.x * 64;
    int t = threadIdx.x;
    int h = t >> 6, o = t & 63;
    {
        int n = t >> 2, q = t & 3;
        float4 v = *(const float4*)&x[((size_t)b*NN + n0 + n)*FI + q*4];
        *(float4*)&xS[n][q*4] = v;
    }
    float wreg[16];
#pragma unroll
    for (int i = 0; i < FI; ++i) wreg[i] = w[(h*FI + i)*FO + o];
    __syncthreads();

    size_t hbase = ((size_t)(b*NH + h)*FO + o) * NN + n0;
    for (int nc = 0; nc < 8; ++nc) {
        float acc[8];
#pragma unroll
        for (int k = 0; k < 8; ++k) {
            int n = nc*8 + k;
            float4 a0 = *(const float4*)&xS[n][0];
            float4 a1 = *(const float4*)&xS[n][4];
            float4 a2 = *(const float4*)&xS[n][8];
            float4 a3 = *(const float4*)&xS[n][12];
            float sA = fmaf(a0.x, wreg[0], fmaf(a0.y, wreg[1], fmaf(a0.z, wreg[2], a0.w*wreg[3])));
            float sB = fmaf(a1.x, wreg[4], fmaf(a1.y, wreg[5], fmaf(a1.z, wreg[6], a1.w*wreg[7])));
            float sC = fmaf(a2.x, wreg[8], fmaf(a2.y, wreg[9], fmaf(a2.z, wreg[10], a2.w*wreg[11])));
            float sD = fmaf(a3.x, wreg[12], fmaf(a3.y, wreg[13], fmaf(a3.z, wreg[14], a3.w*wreg[15])));
            float s = (sA + sB) + (sC + sD);
            acc[k] = s;
            gS[h][n][o] = s;
        }
        uint4 p;
        p.x = pack2(acc[0], acc[1]); p.y = pack2(acc[2], acc[3]);
        p.z = pack2(acc[4], acc[5]); p.w = pack2(acc[6], acc[7]);
        *(uint4*)&hpT[hbase + nc*8] = p;
    }
    {
        int n = o;
        float vs = 0.f, vd = 0.f;
#pragma unroll
        for (int i = 0; i < FI; ++i) {
            float xv = xS[n][i];
            vs = fmaf(xv, wa[h*FI + i], vs);
            vd = fmaf(xv, wa[64 + h*FI + i], vd);
        }
        asrc[(size_t)(b*NH + h)*NN + n0 + n] = vs;
        adst[(size_t)(b*NH + h)*NN + n0 + n] = vd;
    }
    __syncthreads();
#pragma unroll
    for (int r = 0; r < 16; ++r) {
        int idx = t + r*256;
        int n = idx >> 6, oo = idx & 63;
        float g = bias[oo] + ((gS[0][n][oo] + gS[1][n][oo]) + (gS[2][n][oo] + gS[3][n][oo]));
        gat[((size_t)b*NN + n0 + n)*FO + oo] = g;
    }
}

// ---------------- kernel 2: per-row softmax stats (max, 1/sumexp), 1 row/thread ----------------
__global__ __launch_bounds__(256) void k_stats(
    const float* __restrict__ asrc, const float* __restrict__ adst,
    float* __restrict__ rm, float* __restrict__ rr)
{
    int bh = blockIdx.x;              // b*NH + h
    __shared__ float d[NN];
    int t = threadIdx.x;
    for (int j = t; j < NN; j += 256) d[j] = adst[bh * NN + j];
    __syncthreads();
    int i = blockIdx.y * 256 + t;
    float s = asrc[bh * NN + i];
    float m = -INFINITY;
    for (int j = 0; j < NN; ++j) {
        float v = s * d[j];
        v = fmaxf(v, 0.2f * v);
        m = fmaxf(m, v);
    }
    float sum = 0.f;
    for (int j = 0; j < NN; ++j) {
        float v = s * d[j];
        v = fmaxf(v, 0.2f * v);
        sum += __expf(v - m);
    }
    rm[bh * NN + i] = m;
    rr[bh * NN + i] = 1.0f / sum;     // mask applied AFTER softmax
}

// ---------------- kernel 3: MFMA attention, V tile staged via global_load_lds ----------------
__global__ __launch_bounds__(256) void k_attn2(
    const short* __restrict__ hpT, const float* __restrict__ mask,
    const float* __restrict__ asrc, const float* __restrict__ rm, const float* __restrict__ rr,
    const float* __restrict__ adst,
    float* __restrict__ gat)
{
    __shared__ float dS[NH*NN];       // 8KB
    __shared__ char vts[16384];       // V tile [256 (h,o) rows][32 j] bf16, slot-swizzled
    int b = blockIdx.y;
    int i0blk = blockIdx.x * 64;
    int t = threadIdx.x;
#pragma unroll
    for (int r = 0; r < 8; ++r) {
        int idx = t + r*256;
        dS[idx] = adst[(size_t)b*(NH*NN) + idx];
    }
    int wv = t >> 6, lane = t & 63;
    int li = lane & 15, kq = lane >> 4;
    int i = i0blk + wv*16 + li;
    float s[NH], m[NH], rcp[NH];
#pragma unroll
    for (int h = 0; h < NH; ++h) {
        size_t ix = (size_t)(b*NH + h)*NN + i;
        s[h] = asrc[ix]; m[h] = rm[ix]; rcp[h] = rr[ix];
    }
    __syncthreads();
    f32x4 acc[4];
#pragma unroll
    for (int ot = 0; ot < 4; ++ot) acc[ot] = (f32x4)0.f;

    const float* mrow = &mask[((size_t)b*NN + i)*NN];
    for (int jt = 0; jt < 16; ++jt) {
        int j0 = jt*32;
#pragma unroll
        for (int q = 0; q < 4; ++q) {
            int flatB = wv*4096 + q*1024 + lane*16;
            int row = flatB >> 6;
            int slotS = ((flatB >> 4) & 3) ^ ((row >> 1) & 3);
            const short* src = hpT + ((size_t)b*256 + row)*NN + j0 + slotS*8;
            gload16(src, vts + wv*4096 + q*1024);
        }
        __syncthreads();   // drains vmcnt -> tile visible
        float4 mk0 = *(const float4*)&mrow[j0 + kq*8];
        float4 mk1 = *(const float4*)&mrow[j0 + kq*8 + 4];
        float mk[8] = {mk0.x, mk0.y, mk0.z, mk0.w, mk1.x, mk1.y, mk1.z, mk1.w};
#pragma unroll
        for (int h = 0; h < NH; ++h) {
            float4 d0 = *(const float4*)&dS[h*NN + j0 + kq*8];
            float4 d1 = *(const float4*)&dS[h*NN + j0 + kq*8 + 4];
            float dv[8] = {d0.x,d0.y,d0.z,d0.w,d1.x,d1.y,d1.z,d1.w};
            union { bf16x8 v; unsigned u[4]; } pf;
#pragma unroll
            for (int q = 0; q < 4; ++q) {
                float v0 = s[h]*dv[2*q];   v0 = fmaxf(v0, 0.2f*v0);
                float v1 = s[h]*dv[2*q+1]; v1 = fmaxf(v1, 0.2f*v1);
                float e0 = __expf(v0 - m[h]) * rcp[h] * mk[2*q];
                float e1 = __expf(v1 - m[h]) * rcp[h] * mk[2*q+1];
                pf.u[q] = pack2(e0, e1);
            }
#pragma unroll
            for (int ot = 0; ot < 4; ++ot) {
                int row = h*64 + ot*16 + li;
                int slot = kq ^ ((row >> 1) & 3);
                bf16x8 vf = *(bf16x8*)(vts + row*64 + slot*16);
                acc[ot] = __builtin_amdgcn_mfma_f32_16x16x32_bf16(pf.v, vf, acc[ot], 0, 0, 0);
            }
        }
        __syncthreads();   // all reads done before next stage overwrites
    }
#pragma unroll
    for (int ot = 0; ot < 4; ++ot) {
#pragma unroll
        for (int g = 0; g < 4; ++g) {
            int ii = i0blk + wv*16 + kq*4 + g;
            int oo = ot*16 + li;
            size_t ix = ((size_t)b*NN + ii)*FO + oo;
            gat[ix] += acc[ot][g];
        }
    }
}

// ---------------- kernel 4a: convert MLP weights to bf16, transposed (n-major) ----------------
__global__ __launch_bounds__(256) void k_conv(
    const float* __restrict__ W1, const float* __restrict__ W2, const float* __restrict__ W3,
    short* __restrict__ w1t, short* __restrict__ w2t, short* __restrict__ w3t)
{
    int idx = blockIdx.x * 256 + threadIdx.x;
    if (idx < HD1*FO) {
        int n = idx >> 6, k = idx & 63;
        w1t[idx] = (short)f2bf(W1[k*HD1 + n]);
    } else if (idx < HD1*FO + HD2*HD1) {
        int i2 = idx - HD1*FO;
        int n = i2 >> 10, k = i2 & 1023;
        w2t[i2] = (short)f2bf(W2[k*HD2 + n]);
    } else if (idx < HD1*FO + HD2*HD1 + 48*HD2) {
        int i3 = idx - (HD1*FO + HD2*HD1);
        int n = i3 >> 9, k = i3 & 511;
        w3t[i3] = (short)(n < ODIM ? f2bf(W3[k*ODIM + n]) : 0);
    }
}

// ---------------- kernel 4b: GEMM1 [32768x64]@[64x1024] -> relu -> h1g bf16 (global) ----------------
__global__ __launch_bounds__(256, 2) void k_mlpA(
    const float* __restrict__ gat,
    const short* __restrict__ w1t, const float* __restrict__ b1,
    short* __restrict__ h1g)
{
    __shared__ char a0b[8192];        // [64 m][64 k] bf16, XOR-swizzled
    int t = threadIdx.x;
    int lane = t & 63, wave = t >> 6;
    int li = lane & 15, kq = lane >> 4;
    int m0 = blockIdx.x * 64;

    {   // relu(gat) -> bf16 -> a0 (each thread: 1 row-quarter = 16 floats)
        int row = t >> 2, c0 = (t & 3) * 16;
        const float4* g = (const float4*)&gat[(size_t)(m0 + row) * FO + c0];
        float4 v0 = g[0], v1 = g[1], v2 = g[2], v3 = g[3];
        uint4 p0, p1;
        p0.x = pack2(fmaxf(v0.x,0.f), fmaxf(v0.y,0.f));
        p0.y = pack2(fmaxf(v0.z,0.f), fmaxf(v0.w,0.f));
        p0.z = pack2(fmaxf(v1.x,0.f), fmaxf(v1.y,0.f));
        p0.w = pack2(fmaxf(v1.z,0.f), fmaxf(v1.w,0.f));
        p1.x = pack2(fmaxf(v2.x,0.f), fmaxf(v2.y,0.f));
        p1.y = pack2(fmaxf(v2.z,0.f), fmaxf(v2.w,0.f));
        p1.z = pack2(fmaxf(v3.x,0.f), fmaxf(v3.y,0.f));
        p1.w = pack2(fmaxf(v3.z,0.f), fmaxf(v3.w,0.f));
        int base = row*128 + c0*2;
        *(uint4*)(a0b + (base ^ ((row&7)<<4)))      = p0;
        *(uint4*)(a0b + ((base+16) ^ ((row&7)<<4))) = p1;
    }
    __syncthreads();

    for (int c = 0; c < 4; ++c) {     // wave owns 256 n-cols
        int n0 = wave * 256 + c * 64;
        f32x4 acc[4][4];
#pragma unroll
        for (int mt = 0; mt < 4; ++mt)
#pragma unroll
            for (int nt = 0; nt < 4; ++nt) acc[mt][nt] = (f32x4)0.f;
#pragma unroll
        for (int ks = 0; ks < 2; ++ks) {
            int k0 = ks * 32;
            bf16x8 xf[4];
#pragma unroll
            for (int mt = 0; mt < 4; ++mt) {
                int row = mt * 16 + li;
                int addr = (row * 128 + k0 * 2 + kq * 16) ^ ((row & 7) << 4);
                xf[mt] = *(bf16x8*)(a0b + addr);
            }
#pragma unroll
            for (int nt = 0; nt < 4; ++nt) {
                int col = n0 + nt * 16 + li;
                bf16x8 wf = *(const bf16x8*)(w1t + col * 64 + k0 + kq * 8);
#pragma unroll
                for (int mt = 0; mt < 4; ++mt)
                    acc[mt][nt] = __builtin_amdgcn_mfma_f32_16x16x32_bf16(wf, xf[mt], acc[mt][nt], 0, 0, 0);
            }
        }
#pragma unroll
        for (int mt = 0; mt < 4; ++mt)
#pragma unroll
            for (int nt = 0; nt < 4; ++nt) {
                int m = mt * 16 + li;
                int nb = n0 + nt * 16 + kq * 4;
                float4 bb = *(const float4*)&b1[nb];
                float v0 = fmaxf(acc[mt][nt][0] + bb.x, 0.f);
                float v1 = fmaxf(acc[mt][nt][1] + bb.y, 0.f);
                float v2 = fmaxf(acc[mt][nt][2] + bb.z, 0.f);
                float v3 = fmaxf(acc[mt][nt][3] + bb.w, 0.f);
                uint2 pw; pw.x = pack2(v0, v1); pw.y = pack2(v2, v3);
                *(uint2*)&h1g[(size_t)(m0 + m) * HD1 + nb] = pw;
            }
    }
}

// ---------------- kernel 4c: GEMM2 (counted-vmcnt dbuf pipeline) + GEMM3 -> out ----------------
// LDS: 2 x {h1s [64m][32k] 4KB + w2s [512n][32k] 32KB} = 72KB -> 2 blocks/CU.
// Main loop NEVER drains vmcnt to 0 (T4): s_waitcnt vmcnt(9) + raw s_barrier.
// h2 [64][512] bf16 (64KB, XOR-swizzled) aliases the dbuf after GEMM2.
#define BUFSZ 36864
__global__ __launch_bounds__(256, 2) void k_mlpB(
    const short* __restrict__ h1g,
    const short* __restrict__ w2t, const float* __restrict__ b2,
    const short* __restrict__ w3t, const float* __restrict__ b3,
    float* __restrict__ out)
{
    extern __shared__ char smem[];    // 73728 B
    int t = threadIdx.x;
    int lane = t & 63, wave = t >> 6;
    int li = lane & 15, kq = lane >> 4;
    int m0 = blockIdx.x * 64;

    // ---- stage slice ks into buf i: h1s (1 gload/wave) + w2s (8 gloads/wave) = 9 VMEM ops/wave
    auto STAGE = [&](int i, int ks) {
        char* base = smem + i * BUFSZ;
        {
            int row = wave * 16 + (lane >> 2);
            int slotS = (lane & 3) ^ ((row >> 1) & 3);
            const short* src = h1g + (size_t)(m0 + row) * HD1 + ks * 32 + slotS * 8;
            gload16(src, base + wave * 1024);
        }
#pragma unroll
        for (int q = 0; q < 8; ++q) {
            int flatB = wave * 8192 + q * 1024 + lane * 16;
            int n = flatB >> 6;
            int slotS = ((flatB >> 4) & 3) ^ ((n >> 1) & 3);
            const short* src = w2t + (size_t)n * HD1 + ks * 32 + slotS * 8;
            gload16(src, base + 4096 + wave * 8192 + q * 1024);
        }
    };

    f32x4 acc2[4][8];
#pragma unroll
    for (int mt = 0; mt < 4; ++mt)
#pragma unroll
        for (int nt = 0; nt < 8; ++nt) acc2[mt][nt] = (f32x4)0.f;

    STAGE(0, 0);
    STAGE(1, 1);                      // 18 loads/wave in flight
    for (int ks = 0; ks < 32; ++ks) {
        int cur = ks & 1;
        // wait: own cur loads done; next buf's 9 stay in flight (never drain to 0 mid-loop)
        if (ks < 31) { asm volatile("s_waitcnt vmcnt(9)" ::: "memory"); }
        else         { asm volatile("s_waitcnt vmcnt(0)" ::: "memory"); }
        __builtin_amdgcn_sched_barrier(0);
        __builtin_amdgcn_s_barrier();           // all waves: cur buffer fully staged
        __builtin_amdgcn_sched_barrier(0);

        char* base = smem + cur * BUFSZ;
        bf16x8 xf[4], wf[8];
#pragma unroll
        for (int mt = 0; mt < 4; ++mt) {
            int m = mt * 16 + li;
            int slot = kq ^ ((m >> 1) & 3);
            xf[mt] = *(bf16x8*)(base + m * 64 + slot * 16);
        }
#pragma unroll
        for (int nt = 0; nt < 8; ++nt) {
            int n = wave * 128 + nt * 16 + li;
            int slot = kq ^ ((n >> 1) & 3);
            wf[nt] = *(bf16x8*)(base + 4096 + n * 64 + slot * 16);
        }
        asm volatile("s_waitcnt lgkmcnt(0)" ::: "memory");   // my reads in regs
        __builtin_amdgcn_sched_barrier(0);
        __builtin_amdgcn_s_barrier();           // ALL waves done reading cur
        __builtin_amdgcn_sched_barrier(0);
        if (ks < 30) STAGE(cur, ks + 2);        // safe overwrite; latency hides under MFMA+next iter

#pragma unroll
        for (int nt = 0; nt < 8; ++nt)
#pragma unroll
            for (int mt = 0; mt < 4; ++mt)
                acc2[mt][nt] = __builtin_amdgcn_mfma_f32_16x16x32_bf16(wf[nt], xf[mt], acc2[mt][nt], 0, 0, 0);
    }

    // ---- h2 = relu(acc2 + b2) -> bf16 -> LDS [64][512] swizzled (aliases dbuf; all reads done)
#pragma unroll
    for (int mt = 0; mt < 4; ++mt)
#pragma unroll
        for (int nt = 0; nt < 8; ++nt) {
            int m = mt * 16 + li;
            int nb = wave * 128 + nt * 16 + kq * 4;
            float4 bb = *(const float4*)&b2[nb];
            float v0 = fmaxf(acc2[mt][nt][0] + bb.x, 0.f);
            float v1 = fmaxf(acc2[mt][nt][1] + bb.y, 0.f);
            float v2 = fmaxf(acc2[mt][nt][2] + bb.z, 0.f);
            float v3 = fmaxf(acc2[mt][nt][3] + bb.w, 0.f);
            uint2 pw; pw.x = pack2(v0, v1); pw.y = pack2(v2, v3);
            int addr = (m * 1024 + nb * 2) ^ ((m & 7) << 4);
            *(uint2*)(smem + addr) = pw;
        }
    __syncthreads();

    // ---- GEMM3 [64x512]@[512x48]: wave owns 16 m-rows, full K
    f32x4 acc3[3];
#pragma unroll
    for (int nt = 0; nt < 3; ++nt) acc3[nt] = (f32x4)0.f;
#pragma unroll
    for (int ks = 0; ks < 16; ++ks) {
        int k0 = ks * 32;
        int m = wave * 16 + li;
        int addr = (m * 1024 + k0 * 2 + kq * 16) ^ ((m & 7) << 4);
        bf16x8 xf = *(bf16x8*)(smem + addr);
#pragma unroll
        for (int nt = 0; nt < 3; ++nt) {
            int col = nt * 16 + li;
            bf16x8 wf = *(const bf16x8*)(w3t + col * 512 + k0 + kq * 8);
            acc3[nt] = __builtin_amdgcn_mfma_f32_16x16x32_bf16(wf, xf, acc3[nt], 0, 0, 0);
        }
    }
    // out: lane holds m = wave*16+li, n = nt*16 + kq*4 + g
#pragma unroll
    for (int nt = 0; nt < 3; ++nt)
#pragma unroll
        for (int g = 0; g < 4; ++g) {
            int n = nt * 16 + kq * 4 + g;
            if (n < ODIM) {
                int m = wave * 16 + li;
                float s = acc3[nt][g] + b3[n];
                s = 1.f / (1.f + __expf(-s));
                s = fminf(fmaxf(s, 0.01f), 0.99f);
                out[(size_t)(m0 + m) * ODIM + n] = s;
            }
        }
}

extern "C" void kernel_launch(void* const* d_in, const int* in_sizes, int n_in,
                              void* d_out, int out_size, void* d_ws, size_t ws_size,
                              hipStream_t stream)
{
    const float* x     = (const float*)d_in[0];
    const float* mask  = (const float*)d_in[1];
    const float* w     = (const float*)d_in[2];
    const float* a_src = (const float*)d_in[3];
    const float* a_dst = (const float*)d_in[4];
    const float* bias  = (const float*)d_in[5];
    const float* W1    = (const float*)d_in[6];
    const float* b1    = (const float*)d_in[7];
    const float* W2    = (const float*)d_in[8];
    const float* b2    = (const float*)d_in[9];
    const float* W3    = (const float*)d_in[10];
    const float* b3    = (const float*)d_in[11];
    float* out = (float*)d_out;

    char* p = (char*)d_ws;
    // h1g [32768][1024] bf16 (64MB) overlays hpT/asrc/adst/rm/rr (dead before k_mlpA)
    short* h1g = (short*)p;
    short* hpT = (short*)p;  p += (size_t)BB*NH*FO*NN*2;   // 16.78 MB
    float* asrc = (float*)p; p += (size_t)BB*NH*NN*4;
    float* adst = (float*)p; p += (size_t)BB*NH*NN*4;
    float* rm   = (float*)p; p += (size_t)BB*NH*NN*4;
    float* rr   = (float*)p; p += (size_t)BB*NH*NN*4;
    p = (char*)d_ws + (size_t)BB*NN*HD1*2;                 // past h1g (67.1 MB)
    float* gat  = (float*)p; p += (size_t)BB*NN*FO*4;      // 8.39 MB
    short* w1t  = (short*)p; p += (size_t)HD1*FO*2;
    short* w2t  = (short*)p; p += (size_t)HD2*HD1*2;
    short* w3t  = (short*)p; p += (size_t)48*HD2*2;
    float* wa   = (float*)p; p += 128*4;                   // total ~76.7 MB

    k_wa   <<<1, 64, 0, stream>>>(w, a_src, a_dst, wa);
    k_conv <<<(HD1*FO + HD2*HD1 + 48*HD2)/256, 256, 0, stream>>>(W1, W2, W3, w1t, w2t, w3t);
    k_proj2<<<dim3(NN/64, BB), 256, 0, stream>>>(x, w, bias, wa, hpT, asrc, adst, gat);
    k_stats<<<dim3(BB*NH, 2), 256, 0, stream>>>(asrc, adst, rm, rr);
    k_attn2<<<dim3(NN/64, BB), 256, 0, stream>>>(hpT, mask, asrc, rm, rr, adst, gat);
    k_mlpA <<<BB*NN/64, 256, 0, stream>>>(gat, w1t, b1, h1g);
    k_mlpB <<<BB*NN/64, 256, 73728, stream>>>(h1g, w2t, b2, w3t, b3, out);
}

// Round 9
// 167.695 us; speedup vs baseline: 1.2721x; 1.2431x over previous
//
#include <hip/hip_runtime.h>
#include <math.h>

typedef short bf16x8 __attribute__((ext_vector_type(8)));
typedef float f32x4 __attribute__((ext_vector_type(4)));

#define BB 64
#define NN 512
#define NH 4
#define FI 16
#define FO 64
#define HD1 1024
#define HD2 512
#define ODIM 40

__device__ __forceinline__ unsigned short f2bf(float f) {
    unsigned u = __float_as_uint(f);
    u += 0x7fffu + ((u >> 16) & 1u);        // RNE
    return (unsigned short)(u >> 16);
}
__device__ __forceinline__ unsigned pack2(float a, float b) {
    return (unsigned)f2bf(a) | ((unsigned)f2bf(b) << 16);
}
// async global->LDS, 16B per lane; lds dest = wave-uniform base + lane*16
__device__ __forceinline__ void gload16(const void* g, void* l) {
    __builtin_amdgcn_global_load_lds(
        (const __attribute__((address_space(1))) unsigned int*)g,
        (__attribute__((address_space(3))) unsigned int*)l,
        16, 0, 0);
}

// ---------------- kernel 0: wa[h][i] = sum_o w[h][i][o] * a_{src,dst}[h][o] ----------------
__global__ void k_wa(const float* __restrict__ w, const float* __restrict__ a_src,
                     const float* __restrict__ a_dst, float* __restrict__ wa)
{
    int t = threadIdx.x;      // 0..63 = h*16+i
    int h = t >> 4;
    float s = 0.f, d = 0.f;
    for (int o = 0; o < FO; ++o) {
        float wv = w[t*FO + o];
        s = fmaf(wv, a_src[h*FO + o], s);
        d = fmaf(wv, a_dst[h*FO + o], d);
    }
    wa[t] = s; wa[64 + t] = d;
}

// ---------------- kernel 1: projection -> hpT bf16 (transposed), asrc/adst, gat=bias+skip ----------------
__global__ __launch_bounds__(256) void k_proj2(
    const float* __restrict__ x, const float* __restrict__ w,
    const float* __restrict__ bias, const float* __restrict__ wa,
    short* __restrict__ hpT,           // [B*H][64 o][512 n] bf16
    float* __restrict__ asrc, float* __restrict__ adst,
    float* __restrict__ gat)
{
    __shared__ float xS[64][20];
    __shared__ float gS[NH][64][64];
    int b = blockIdx.y;
    int n0 = blockIdx.x * 64;
    int t = threadIdx.x;
    int h = t >> 6, o = t & 63;
    {
        int n = t >> 2, q = t & 3;
        float4 v = *(const float4*)&x[((size_t)b*NN + n0 + n)*FI + q*4];
        *(float4*)&xS[n][q*4] = v;
    }
    float wreg[16];
#pragma unroll
    for (int i = 0; i < FI; ++i) wreg[i] = w[(h*FI + i)*FO + o];
    __syncthreads();

    size_t hbase = ((size_t)(b*NH + h)*FO + o) * NN + n0;
    for (int nc = 0; nc < 8; ++nc) {
        float acc[8];
#pragma unroll
        for (int k = 0; k < 8; ++k) {
            int n = nc*8 + k;
            float4 a0 = *(const float4*)&xS[n][0];
            float4 a1 = *(const float4*)&xS[n][4];
            float4 a2 = *(const float4*)&xS[n][8];
            float4 a3 = *(const float4*)&xS[n][12];
            float sA = fmaf(a0.x, wreg[0], fmaf(a0.y, wreg[1], fmaf(a0.z, wreg[2], a0.w*wreg[3])));
            float sB = fmaf(a1.x, wreg[4], fmaf(a1.y, wreg[5], fmaf(a1.z, wreg[6], a1.w*wreg[7])));
            float sC = fmaf(a2.x, wreg[8], fmaf(a2.y, wreg[9], fmaf(a2.z, wreg[10], a2.w*wreg[11])));
            float sD = fmaf(a3.x, wreg[12], fmaf(a3.y, wreg[13], fmaf(a3.z, wreg[14], a3.w*wreg[15])));
            float s = (sA + sB) + (sC + sD);
            acc[k] = s;
            gS[h][n][o] = s;
        }
        uint4 p;
        p.x = pack2(acc[0], acc[1]); p.y = pack2(acc[2], acc[3]);
        p.z = pack2(acc[4], acc[5]); p.w = pack2(acc[6], acc[7]);
        *(uint4*)&hpT[hbase + nc*8] = p;
    }
    {
        int n = o;
        float vs = 0.f, vd = 0.f;
#pragma unroll
        for (int i = 0; i < FI; ++i) {
            float xv = xS[n][i];
            vs = fmaf(xv, wa[h*FI + i], vs);
            vd = fmaf(xv, wa[64 + h*FI + i], vd);
        }
        asrc[(size_t)(b*NH + h)*NN + n0 + n] = vs;
        adst[(size_t)(b*NH + h)*NN + n0 + n] = vd;
    }
    __syncthreads();
#pragma unroll
    for (int r = 0; r < 16; ++r) {
        int idx = t + r*256;
        int n = idx >> 6, oo = idx & 63;
        float g = bias[oo] + ((gS[0][n][oo] + gS[1][n][oo]) + (gS[2][n][oo] + gS[3][n][oo]));
        gat[((size_t)b*NN + n0 + n)*FO + oo] = g;
    }
}

// ---------------- kernel 2: MFMA attention with FUSED softmax stats ----------------
// Analytic row-max: m = leaky(s * (s>=0 ? dmax : dmin)) == scanned max (monotone).
// Denominator: per-lane partial sums of unmasked u=exp(l-m) during the one exp pass;
// per-HEAD f32 accumulators; normalize by 1/S_h in the epilogue.
__global__ __launch_bounds__(256) void k_attn2(
    const short* __restrict__ hpT, const float* __restrict__ mask,
    const float* __restrict__ asrc, const float* __restrict__ adst,
    float* __restrict__ gat)
{
    __shared__ float dS[NH*NN];       // 8KB
    __shared__ char vts[16384];       // V tile [256 (h,o) rows][32 j] bf16, slot-swizzled
    __shared__ float dmaxS[NH], dminS[NH];
    int b = blockIdx.y;
    int i0blk = blockIdx.x * 64;
    int t = threadIdx.x;
#pragma unroll
    for (int r = 0; r < 8; ++r) {
        int idx = t + r*256;
        dS[idx] = adst[(size_t)b*(NH*NN) + idx];
    }
    __syncthreads();
    int wv = t >> 6, lane = t & 63;
    {   // wave wv reduces head wv's d-range
        float mx = -INFINITY, mn = INFINITY;
        const float* dh = &dS[wv*NN];
#pragma unroll
        for (int q = 0; q < 8; ++q) {
            float v = dh[lane*8 + q];
            mx = fmaxf(mx, v); mn = fminf(mn, v);
        }
#pragma unroll
        for (int off = 1; off < 64; off <<= 1) {
            mx = fmaxf(mx, __shfl_xor(mx, off));
            mn = fminf(mn, __shfl_xor(mn, off));
        }
        if (lane == 0) { dmaxS[wv] = mx; dminS[wv] = mn; }
    }
    __syncthreads();
    int li = lane & 15, kq = lane >> 4;
    int i = i0blk + wv*16 + li;
    float s[NH], m[NH], Ssum[NH];
#pragma unroll
    for (int h = 0; h < NH; ++h) {
        s[h] = asrc[(size_t)(b*NH + h)*NN + i];
        float dm = s[h] >= 0.f ? dmaxS[h] : dminS[h];
        float l = s[h] * dm;
        m[h] = fmaxf(l, 0.2f*l);      // == max_j leaky(s*d_j)
        Ssum[h] = 0.f;
    }
    f32x4 accH[NH][4];
#pragma unroll
    for (int h = 0; h < NH; ++h)
#pragma unroll
        for (int ot = 0; ot < 4; ++ot) accH[h][ot] = (f32x4)0.f;

    const float* mrow = &mask[((size_t)b*NN + i)*NN];
    for (int jt = 0; jt < 16; ++jt) {
        int j0 = jt*32;
#pragma unroll
        for (int q = 0; q < 4; ++q) {
            int flatB = wv*4096 + q*1024 + lane*16;
            int row = flatB >> 6;
            int slotS = ((flatB >> 4) & 3) ^ ((row >> 1) & 3);
            const short* src = hpT + ((size_t)b*256 + row)*NN + j0 + slotS*8;
            gload16(src, vts + wv*4096 + q*1024);
        }
        __syncthreads();   // drains vmcnt -> tile visible
        float4 mk0 = *(const float4*)&mrow[j0 + kq*8];
        float4 mk1 = *(const float4*)&mrow[j0 + kq*8 + 4];
        float mk[8] = {mk0.x, mk0.y, mk0.z, mk0.w, mk1.x, mk1.y, mk1.z, mk1.w};
#pragma unroll
        for (int h = 0; h < NH; ++h) {
            float4 d0 = *(const float4*)&dS[h*NN + j0 + kq*8];
            float4 d1 = *(const float4*)&dS[h*NN + j0 + kq*8 + 4];
            float dv[8] = {d0.x,d0.y,d0.z,d0.w,d1.x,d1.y,d1.z,d1.w};
            float u[8];
#pragma unroll
            for (int q = 0; q < 8; ++q) {
                float v = s[h]*dv[q];
                v = fmaxf(v, 0.2f*v);
                u[q] = __expf(v - m[h]);
            }
            Ssum[h] += ((u[0]+u[1]) + (u[2]+u[3])) + ((u[4]+u[5]) + (u[6]+u[7]));
            union { bf16x8 v; unsigned uu[4]; } pf;
#pragma unroll
            for (int q = 0; q < 4; ++q)
                pf.uu[q] = pack2(u[2*q]*mk[2*q], u[2*q+1]*mk[2*q+1]);
#pragma unroll
            for (int ot = 0; ot < 4; ++ot) {
                int row = h*64 + ot*16 + li;
                int slot = kq ^ ((row >> 1) & 3);
                bf16x8 vf = *(bf16x8*)(vts + row*64 + slot*16);
                accH[h][ot] = __builtin_amdgcn_mfma_f32_16x16x32_bf16(pf.v, vf, accH[h][ot], 0, 0, 0);
            }
        }
        __syncthreads();   // all reads done before next stage overwrites
    }
    // reduce row-sums across the 4 kq groups (lanes sharing li)
#pragma unroll
    for (int h = 0; h < NH; ++h) {
        Ssum[h] += __shfl_xor(Ssum[h], 16);
        Ssum[h] += __shfl_xor(Ssum[h], 32);
    }
    // D rows are i = kq*4+g; S for that row lives at lane (kq*4+g) (li'=row, kq'=0)
    float rinv[NH][4];
#pragma unroll
    for (int h = 0; h < NH; ++h)
#pragma unroll
        for (int g = 0; g < 4; ++g)
            rinv[h][g] = 1.0f / __shfl(Ssum[h], kq*4 + g);
#pragma unroll
    for (int ot = 0; ot < 4; ++ot) {
#pragma unroll
        for (int g = 0; g < 4; ++g) {
            int ii = i0blk + wv*16 + kq*4 + g;
            int oo = ot*16 + li;
            size_t ix = ((size_t)b*NN + ii)*FO + oo;
            float add = accH[0][ot][g]*rinv[0][g] + accH[1][ot][g]*rinv[1][g]
                      + accH[2][ot][g]*rinv[2][g] + accH[3][ot][g]*rinv[3][g];
            gat[ix] += add;
        }
    }
}

// ---------------- kernel 4a: convert MLP weights to bf16, transposed (n-major) ----------------
__global__ __launch_bounds__(256) void k_conv(
    const float* __restrict__ W1, const float* __restrict__ W2, const float* __restrict__ W3,
    short* __restrict__ w1t, short* __restrict__ w2t, short* __restrict__ w3t)
{
    int idx = blockIdx.x * 256 + threadIdx.x;
    if (idx < HD1*FO) {
        int n = idx >> 6, k = idx & 63;
        w1t[idx] = (short)f2bf(W1[k*HD1 + n]);
    } else if (idx < HD1*FO + HD2*HD1) {
        int i2 = idx - HD1*FO;
        int n = i2 >> 10, k = i2 & 1023;
        w2t[i2] = (short)f2bf(W2[k*HD2 + n]);
    } else if (idx < HD1*FO + HD2*HD1 + 48*HD2) {
        int i3 = idx - (HD1*FO + HD2*HD1);
        int n = i3 >> 9, k = i3 & 511;
        w3t[i3] = (short)(n < ODIM ? f2bf(W3[k*ODIM + n]) : 0);
    }
}

// ---------------- kernel 4b: GEMM1 [32768x64]@[64x1024] -> relu -> h1g bf16 (global) ----------------
__global__ __launch_bounds__(256, 2) void k_mlpA(
    const float* __restrict__ gat,
    const short* __restrict__ w1t, const float* __restrict__ b1,
    short* __restrict__ h1g)
{
    __shared__ char a0b[8192];        // [64 m][64 k] bf16, XOR-swizzled
    int t = threadIdx.x;
    int lane = t & 63, wave = t >> 6;
    int li = lane & 15, kq = lane >> 4;
    int m0 = blockIdx.x * 64;

    {   // relu(gat) -> bf16 -> a0 (each thread: 1 row-quarter = 16 floats)
        int row = t >> 2, c0 = (t & 3) * 16;
        const float4* g = (const float4*)&gat[(size_t)(m0 + row) * FO + c0];
        float4 v0 = g[0], v1 = g[1], v2 = g[2], v3 = g[3];
        uint4 p0, p1;
        p0.x = pack2(fmaxf(v0.x,0.f), fmaxf(v0.y,0.f));
        p0.y = pack2(fmaxf(v0.z,0.f), fmaxf(v0.w,0.f));
        p0.z = pack2(fmaxf(v1.x,0.f), fmaxf(v1.y,0.f));
        p0.w = pack2(fmaxf(v1.z,0.f), fmaxf(v1.w,0.f));
        p1.x = pack2(fmaxf(v2.x,0.f), fmaxf(v2.y,0.f));
        p1.y = pack2(fmaxf(v2.z,0.f), fmaxf(v2.w,0.f));
        p1.z = pack2(fmaxf(v3.x,0.f), fmaxf(v3.y,0.f));
        p1.w = pack2(fmaxf(v3.z,0.f), fmaxf(v3.w,0.f));
        int base = row*128 + c0*2;
        *(uint4*)(a0b + (base ^ ((row&7)<<4)))      = p0;
        *(uint4*)(a0b + ((base+16) ^ ((row&7)<<4))) = p1;
    }
    __syncthreads();

    for (int c = 0; c < 4; ++c) {     // wave owns 256 n-cols
        int n0 = wave * 256 + c * 64;
        f32x4 acc[4][4];
#pragma unroll
        for (int mt = 0; mt < 4; ++mt)
#pragma unroll
            for (int nt = 0; nt < 4; ++nt) acc[mt][nt] = (f32x4)0.f;
#pragma unroll
        for (int ks = 0; ks < 2; ++ks) {
            int k0 = ks * 32;
            bf16x8 xf[4];
#pragma unroll
            for (int mt = 0; mt < 4; ++mt) {
                int row = mt * 16 + li;
                int addr = (row * 128 + k0 * 2 + kq * 16) ^ ((row & 7) << 4);
                xf[mt] = *(bf16x8*)(a0b + addr);
            }
#pragma unroll
            for (int nt = 0; nt < 4; ++nt) {
                int col = n0 + nt * 16 + li;
                bf16x8 wf = *(const bf16x8*)(w1t + col * 64 + k0 + kq * 8);
#pragma unroll
                for (int mt = 0; mt < 4; ++mt)
                    acc[mt][nt] = __builtin_amdgcn_mfma_f32_16x16x32_bf16(wf, xf[mt], acc[mt][nt], 0, 0, 0);
            }
        }
#pragma unroll
        for (int mt = 0; mt < 4; ++mt)
#pragma unroll
            for (int nt = 0; nt < 4; ++nt) {
                int m = mt * 16 + li;
                int nb = n0 + nt * 16 + kq * 4;
                float4 bb = *(const float4*)&b1[nb];
                float v0 = fmaxf(acc[mt][nt][0] + bb.x, 0.f);
                float v1 = fmaxf(acc[mt][nt][1] + bb.y, 0.f);
                float v2 = fmaxf(acc[mt][nt][2] + bb.z, 0.f);
                float v3 = fmaxf(acc[mt][nt][3] + bb.w, 0.f);
                uint2 pw; pw.x = pack2(v0, v1); pw.y = pack2(v2, v3);
                *(uint2*)&h1g[(size_t)(m0 + m) * HD1 + nb] = pw;
            }
    }
}

// ---------------- kernel 4c: GEMM2+3, M=128/block, 8 waves, 1 block/CU, counted-vmcnt dbuf ----------------
// LDS: 2 x {h1s [128m][32k] 8KB + w2s [512n][32k] 32KB} = 80KB dbuf;
// h2 [128][512] bf16 (128KB, swizzled) overwrites it for GEMM3. smem = 131072.
#define BUFSZ 40960
__global__ __launch_bounds__(512, 2) void k_mlpB(
    const short* __restrict__ h1g,
    const short* __restrict__ w2t, const float* __restrict__ b2,
    const short* __restrict__ w3t, const float* __restrict__ b3,
    float* __restrict__ out)
{
    extern __shared__ char smem[];    // 131072 B
    int t = threadIdx.x;
    int lane = t & 63, wave = t >> 6;
    int li = lane & 15, kq = lane >> 4;
    int m0 = blockIdx.x * 128;

    // ---- stage slice ks into buf i: h1s (1 gload/wave) + w2s (4 gloads/wave) = 5 VMEM/wave
    auto STAGE = [&](int i, int ks) {
        char* base = smem + i * BUFSZ;
        {
            int row = wave * 16 + (lane >> 2);
            int slotS = (lane & 3) ^ ((row >> 1) & 3);
            const short* src = h1g + (size_t)(m0 + row) * HD1 + ks * 32 + slotS * 8;
            gload16(src, base + wave * 1024);
        }
#pragma unroll
        for (int q = 0; q < 4; ++q) {
            int flatB = wave * 4096 + q * 1024 + lane * 16;
            int n = flatB >> 6;
            int slotS = ((flatB >> 4) & 3) ^ ((n >> 1) & 3);
            const short* src = w2t + (size_t)n * HD1 + ks * 32 + slotS * 8;
            gload16(src, base + 8192 + wave * 4096 + q * 1024);
        }
    };

    f32x4 acc2[8][4];
#pragma unroll
    for (int mt = 0; mt < 8; ++mt)
#pragma unroll
        for (int nt = 0; nt < 4; ++nt) acc2[mt][nt] = (f32x4)0.f;

    STAGE(0, 0);
    STAGE(1, 1);                      // 10 loads/wave in flight
    for (int ks = 0; ks < 32; ++ks) {
        int cur = ks & 1;
        if (ks < 31) { asm volatile("s_waitcnt vmcnt(5)" ::: "memory"); }
        else         { asm volatile("s_waitcnt vmcnt(0)" ::: "memory"); }
        __builtin_amdgcn_sched_barrier(0);
        __builtin_amdgcn_s_barrier();           // all waves: cur buffer fully staged
        __builtin_amdgcn_sched_barrier(0);

        char* base = smem + cur * BUFSZ;
        bf16x8 xf[8], wf[4];
#pragma unroll
        for (int mt = 0; mt < 8; ++mt) {
            int m = mt * 16 + li;
            int slot = kq ^ ((m >> 1) & 3);
            xf[mt] = *(bf16x8*)(base + m * 64 + slot * 16);
        }
#pragma unroll
        for (int nt = 0; nt < 4; ++nt) {
            int n = wave * 64 + nt * 16 + li;
            int slot = kq ^ ((n >> 1) & 3);
            wf[nt] = *(bf16x8*)(base + 8192 + n * 64 + slot * 16);
        }
        asm volatile("s_waitcnt lgkmcnt(0)" ::: "memory");   // my reads in regs
        __builtin_amdgcn_sched_barrier(0);
        __builtin_amdgcn_s_barrier();           // ALL waves done reading cur
        __builtin_amdgcn_sched_barrier(0);
        if (ks < 30) STAGE(cur, ks + 2);        // safe overwrite; 2-iter latency window

#pragma unroll
        for (int nt = 0; nt < 4; ++nt)
#pragma unroll
            for (int mt = 0; mt < 8; ++mt)
                acc2[mt][nt] = __builtin_amdgcn_mfma_f32_16x16x32_bf16(wf[nt], xf[mt], acc2[mt][nt], 0, 0, 0);
    }
    __syncthreads();

    // ---- h2 = relu(acc2 + b2) -> bf16 -> LDS [128][512] swizzled (overwrites dbuf)
#pragma unroll
    for (int mt = 0; mt < 8; ++mt)
#pragma unroll
        for (int nt = 0; nt < 4; ++nt) {
            int m = mt * 16 + li;
            int nb = wave * 64 + nt * 16 + kq * 4;
            float4 bb = *(const float4*)&b2[nb];
            float v0 = fmaxf(acc2[mt][nt][0] + bb.x, 0.f);
            float v1 = fmaxf(acc2[mt][nt][1] + bb.y, 0.f);
            float v2 = fmaxf(acc2[mt][nt][2] + bb.z, 0.f);
            float v3 = fmaxf(acc2[mt][nt][3] + bb.w, 0.f);
            uint2 pw; pw.x = pack2(v0, v1); pw.y = pack2(v2, v3);
            int addr = (m * 1024 + nb * 2) ^ ((m & 7) << 4);
            *(uint2*)(smem + addr) = pw;
        }
    __syncthreads();

    // ---- GEMM3 [128x512]@[512x48]: wave owns 16 m-rows, full K
    f32x4 acc3[3];
#pragma unroll
    for (int nt = 0; nt < 3; ++nt) acc3[nt] = (f32x4)0.f;
#pragma unroll
    for (int ks = 0; ks < 16; ++ks) {
        int k0 = ks * 32;
        int m = wave * 16 + li;
        int addr = (m * 1024 + k0 * 2 + kq * 16) ^ ((m & 7) << 4);
        bf16x8 xf = *(bf16x8*)(smem + addr);
#pragma unroll
        for (int nt = 0; nt < 3; ++nt) {
            int col = nt * 16 + li;
            bf16x8 wf = *(const bf16x8*)(w3t + col * 512 + k0 + kq * 8);
            acc3[nt] = __builtin_amdgcn_mfma_f32_16x16x32_bf16(wf, xf, acc3[nt], 0, 0, 0);
        }
    }
#pragma unroll
    for (int nt = 0; nt < 3; ++nt)
#pragma unroll
        for (int g = 0; g < 4; ++g) {
            int n = nt * 16 + kq * 4 + g;
            if (n < ODIM) {
                int m = wave * 16 + li;
                float s = acc3[nt][g] + b3[n];
                s = 1.f / (1.f + __expf(-s));
                s = fminf(fmaxf(s, 0.01f), 0.99f);
                out[(size_t)(m0 + m) * ODIM + n] = s;
            }
        }
}

extern "C" void kernel_launch(void* const* d_in, const int* in_sizes, int n_in,
                              void* d_out, int out_size, void* d_ws, size_t ws_size,
                              hipStream_t stream)
{
    const float* x     = (const float*)d_in[0];
    const float* mask  = (const float*)d_in[1];
    const float* w     = (const float*)d_in[2];
    const float* a_src = (const float*)d_in[3];
    const float* a_dst = (const float*)d_in[4];
    const float* bias  = (const float*)d_in[5];
    const float* W1    = (const float*)d_in[6];
    const float* b1    = (const float*)d_in[7];
    const float* W2    = (const float*)d_in[8];
    const float* b2    = (const float*)d_in[9];
    const float* W3    = (const float*)d_in[10];
    const float* b3    = (const float*)d_in[11];
    float* out = (float*)d_out;

    char* p = (char*)d_ws;
    // h1g [32768][1024] bf16 (64MB) overlays hpT/asrc/adst (dead before k_mlpA)
    short* h1g = (short*)p;
    short* hpT = (short*)p;  p += (size_t)BB*NH*FO*NN*2;   // 16.78 MB
    float* asrc = (float*)p; p += (size_t)BB*NH*NN*4;
    float* adst = (float*)p; p += (size_t)BB*NH*NN*4;
    p = (char*)d_ws + (size_t)BB*NN*HD1*2;                 // past h1g (67.1 MB)
    float* gat  = (float*)p; p += (size_t)BB*NN*FO*4;      // 8.39 MB
    short* w1t  = (short*)p; p += (size_t)HD1*FO*2;
    short* w2t  = (short*)p; p += (size_t)HD2*HD1*2;
    short* w3t  = (short*)p; p += (size_t)48*HD2*2;
    float* wa   = (float*)p; p += 128*4;                   // total ~76.7 MB

    k_wa   <<<1, 64, 0, stream>>>(w, a_src, a_dst, wa);
    k_conv <<<(HD1*FO + HD2*HD1 + 48*HD2)/256, 256, 0, stream>>>(W1, W2, W3, w1t, w2t, w3t);
    k_proj2<<<dim3(NN/64, BB), 256, 0, stream>>>(x, w, bias, wa, hpT, asrc, adst, gat);
    k_attn2<<<dim3(NN/64, BB), 256, 0, stream>>>(hpT, mask, asrc, adst, gat);
    k_mlpA <<<BB*NN/64, 256, 0, stream>>>(gat, w1t, b1, h1g);
    k_mlpB <<<BB*NN/128, 512, 131072, stream>>>(h1g, w2t, b2, w3t, b3, out);
}